// Round 5
// baseline (863.468 us; speedup 1.0000x reference)
//
#include <hip/hip_runtime.h>

typedef unsigned short u16;
typedef __attribute__((ext_vector_type(8))) short short8;
typedef __attribute__((ext_vector_type(4))) float f32x4;

#define N_NODES 100000
#define N_EDGES 1600000
#define F_IN    128
#define HD      64
#define LN_EPS  1e-5f

// Transposed weights: WT[m][col][k], 4 matrices x 64 cols x 128 k (u16 bf16).
// m: 0=Q 1=K 2=V 3=Skip. Used by proj_kv (K,V fragments) and attn (Q,S dots).
__device__ u16 g_WT[4 * HD * F_IN];

// ---------- bf16 helpers ----------
__device__ __forceinline__ float bf2f(u16 u) {
    union { unsigned int i; float f; } x;
    x.i = ((unsigned int)u) << 16;
    return x.f;
}
__device__ __forceinline__ u16 f2bf(float f) {
    unsigned int u;
    __builtin_memcpy(&u, &f, 4);
    unsigned int r = u + 0x7FFFu + ((u >> 16) & 1u);   // RNE
    return (u16)(r >> 16);
}

// 4-element load helper for the fp32 fallback path.
__device__ __forceinline__ void ld4f(const float* p, int idx, float o[4]) {
    const float4 v = *reinterpret_cast<const float4*>(p + idx);
    o[0] = v.x; o[1] = v.y; o[2] = v.z; o[3] = v.w;
}

// ---------- Kernel 0: dtype probe ----------
__global__ __launch_bounds__(64) void probe_r12(const u16* __restrict__ feat,
                                                int* __restrict__ mode)
{
    const int lane = threadIdx.x;
    float m = 0.f;
    #pragma unroll
    for (int i = 0; i < 4; ++i)
        m = fmaxf(m, fabsf(bf2f(feat[lane * 4 + i])));
    #pragma unroll
    for (int o = 1; o < 64; o <<= 1) m = fmaxf(m, __shfl_xor(m, o));
    if (lane == 0) *mode = (m > 1000.f) ? 1 : 0;
}

// ---------- Kernel 0b: transpose W (bf16 mode only; 64KB total) ----------
__global__ __launch_bounds__(256) void wtrans_r12(
    const void* __restrict__ Wq, const void* __restrict__ Wk,
    const void* __restrict__ Wv, const void* __restrict__ Ws,
    const int* __restrict__ mode_p)
{
    if (*mode_p != 0) return;
    const int m  = blockIdx.x >> 2;
    const int kg = blockIdx.x & 3;
    const u16* W = (const u16*)((m == 0) ? Wq : (m == 1) ? Wk : (m == 2) ? Wv : Ws);
    const int t  = threadIdx.x;
    const int k  = kg * 32 + (t >> 3);
    const int c0 = (t & 7) * 8;
    union { uint4 v; u16 s[8]; } row;
    row.v = *reinterpret_cast<const uint4*>(W + k * HD + c0);
    u16* out = g_WT + m * HD * F_IN;
    #pragma unroll
    for (int j = 0; j < 8; ++j)
        out[(c0 + j) * F_IN + k] = row.s[j];
}

// ---------- Kernel 1: K/V projection only (Q and Skip fused into attn) ------
// Block = 4 waves over 128 nodes: wave pair p = w>>1 owns nodes
// [bid*128 + p*64, +64); within a pair, w&1 selects K (0) or V (1).
// Same verified MFMA structure as r9-r11: D = W^T * F^T, swizzled LDS
// epilogue, interleaved KV (K low u16, V high u16) so attn's gather of one
// u32 per lane is unchanged. Traffic: 25.6MB read + 25.6MB write (was 77MB).
__global__ __launch_bounds__(256) void projkv_r12(
    const void* __restrict__ feature,
    const void* __restrict__ Wk, const void* __restrict__ bk,
    const void* __restrict__ Wv, const void* __restrict__ bv,
    unsigned int* __restrict__ KV,
    const int* __restrict__ mode_p)
{
    const int mode = *mode_p;
    const int tid  = threadIdx.x;
    const int w    = tid >> 6;
    const int lane = tid & 63;
    const int p    = w >> 1;         // node-pair 0/1
    const int is_v = w & 1;          // 0 = K, 1 = V

    __shared__ u16 lk[2][16 * 64];
    __shared__ u16 lv[2][16 * 64];

    if (mode == 0) {
        const u16* F = (const u16*)feature;
        const int h = lane >> 4;    // 0..3
        const int c = lane & 15;    // 0..15

        // A fragments (W^T) from g_WT (matrix 1=K or 2=V).
        const u16* WT = g_WT + (is_v ? 2 : 1) * HD * F_IN;
        short8 wfrag[4][4];
        #pragma unroll
        for (int ct = 0; ct < 4; ++ct) {
            const int col = ct * 16 + c;
            #pragma unroll
            for (int ks = 0; ks < 4; ++ks)
                wfrag[ct][ks] = *reinterpret_cast<const short8*>(
                    WT + col * F_IN + ks * 32 + h * 8);
        }

        const u16* bb = (const u16*)(is_v ? bv : bk);
        float bias_f[4][4];
        #pragma unroll
        for (int ct = 0; ct < 4; ++ct) {
            const ushort4 bu =
                *reinterpret_cast<const ushort4*>(bb + ct * 16 + h * 4);
            bias_f[ct][0] = bf2f(bu.x); bias_f[ct][1] = bf2f(bu.y);
            bias_f[ct][2] = bf2f(bu.z); bias_f[ct][3] = bf2f(bu.w);
        }

        u16* Lmine = is_v ? lv[p] : lk[p];

        // Prefetch tile 0 feature fragments (rows nbase0 + c).
        short8 fr[2][4];
        {
            const int nb0 = blockIdx.x * 128 + p * 64;
            if (nb0 < N_NODES) {
                const size_t arow = (size_t)(nb0 + c) * F_IN;
                #pragma unroll
                for (int ks = 0; ks < 4; ++ks)
                    fr[0][ks] = *reinterpret_cast<const short8*>(
                        F + arow + ks * 32 + h * 8);
            }
        }

        #pragma unroll
        for (int t = 0; t < 4; ++t) {
            const int nbase = blockIdx.x * 128 + p * 64 + t * 16;
            const bool act = (nbase < N_NODES);      // wave-uniform
            const int cur = t & 1, nxt = cur ^ 1;

            if (act) {
                // Prefetch next tile under this tile's compute/epilogue.
                const int nb2 = nbase + 16;
                if (t < 3 && nb2 < N_NODES) {
                    const size_t arow = (size_t)(nb2 + c) * F_IN;
                    #pragma unroll
                    for (int ks = 0; ks < 4; ++ks)
                        fr[nxt][ks] = *reinterpret_cast<const short8*>(
                            F + arow + ks * 32 + h * 8);
                }

                f32x4 acc[4];
                #pragma unroll
                for (int ct = 0; ct < 4; ++ct) acc[ct] = (f32x4){0.f, 0.f, 0.f, 0.f};
                #pragma unroll
                for (int ks = 0; ks < 4; ++ks)
                    #pragma unroll
                    for (int ct = 0; ct < 4; ++ct)
                        acc[ct] = __builtin_amdgcn_mfma_f32_16x16x32_bf16(
                            wfrag[ct][ks], fr[cur][ks], acc[ct], 0, 0, 0);

                // Pack ushort4 per ct into swizzled LDS (row = c = node-local).
                #pragma unroll
                for (int ct = 0; ct < 4; ++ct) {
                    ushort4 pk;
                    pk.x = f2bf(acc[ct][0] + bias_f[ct][0]);
                    pk.y = f2bf(acc[ct][1] + bias_f[ct][1]);
                    pk.z = f2bf(acc[ct][2] + bias_f[ct][2]);
                    pk.w = f2bf(acc[ct][3] + bias_f[ct][3]);
                    const int bo = (ct * 32 + h * 8) ^ ((c & 7) << 4);
                    *reinterpret_cast<ushort4*>(
                        reinterpret_cast<char*>(Lmine) + c * 128 + bo) = pk;
                }
            }
            __syncthreads();

            // Cooperative interleave+store of BOTH 16-node tiles (8KB total).
            {
                const int p2   = tid >> 7;         // which tile pair
                const int tt   = tid & 127;
                const int krow = tt >> 3;          // 0..15 node-local row
                const int c8   = tt & 7;           // 0..7
                const int nodeS = blockIdx.x * 128 + p2 * 64 + t * 16 + krow;
                if (nodeS < N_NODES) {
                    #pragma unroll
                    for (int sub = 0; sub < 2; ++sub) {
                        const int c4 = c8 * 2 + sub;
                        const int ko = (c4 * 8) ^ ((krow & 7) << 4);
                        const ushort4 kk = *reinterpret_cast<const ushort4*>(
                            reinterpret_cast<const char*>(lk[p2]) + krow * 128 + ko);
                        const ushort4 vv = *reinterpret_cast<const ushort4*>(
                            reinterpret_cast<const char*>(lv[p2]) + krow * 128 + ko);
                        uint4 o;
                        o.x = (unsigned)kk.x | ((unsigned)vv.x << 16);
                        o.y = (unsigned)kk.y | ((unsigned)vv.y << 16);
                        o.z = (unsigned)kk.z | ((unsigned)vv.z << 16);
                        o.w = (unsigned)kk.w | ((unsigned)vv.w << 16);
                        *reinterpret_cast<uint4*>(
                            KV + (size_t)nodeS * HD + c4 * 4) = o;
                    }
                }
            }
            __syncthreads();
        }
    } else {
        // ---------- fp32 fallback (inert in practice) ----------
        const float* Wf = (const float*)(is_v ? Wv : Wk);
        const float* bf = (const float*)(is_v ? bv : bk);
        const float* Ff = (const float*)feature;
        u16* KVu = (u16*)KV;
        const int colg  = lane & 15;
        const int nodeg = lane >> 4;
        const int c0    = colg * 4;

        for (int st = 0; st < 4; ++st) {
            const int tb = blockIdx.x * 128 + p * 64 + st * 16;
            if (tb >= N_NODES) break;            // wave-uniform; no barriers here
            const int node_base = tb + nodeg * 4;

            float acc[4][4];
            #pragma unroll
            for (int n = 0; n < 4; ++n)
                #pragma unroll
                for (int cc = 0; cc < 4; ++cc) acc[n][cc] = 0.f;

            for (int k = 0; k < F_IN; k += 4) {
                float wv4[4][4];
                #pragma unroll
                for (int kk = 0; kk < 4; ++kk)
                    ld4f(Wf, (k + kk) * HD + c0, wv4[kk]);
                #pragma unroll
                for (int n = 0; n < 4; ++n) {
                    float f[4];
                    ld4f(Ff, (node_base + n) * F_IN + k, f);
                    #pragma unroll
                    for (int cc = 0; cc < 4; ++cc)
                        acc[n][cc] += f[0] * wv4[0][cc] + f[1] * wv4[1][cc]
                                    + f[2] * wv4[2][cc] + f[3] * wv4[3][cc];
                }
            }

            float bias[4];
            ld4f(bf, c0, bias);

            #pragma unroll
            for (int n = 0; n < 4; ++n) {
                const int node = node_base + n;
                #pragma unroll
                for (int cc = 0; cc < 4; ++cc)
                    KVu[(size_t)node * 2 * HD + 2 * (c0 + cc) + is_v] =
                        f2bf(acc[n][cc] + bias[cc]);
            }
        }
    }
}

// ---------- Kernel 2: degree histogram ----------
__global__ __launch_bounds__(256) void hist_r12(const int* __restrict__ dst,
                                                int* __restrict__ deg)
{
    int e = blockIdx.x * 256 + threadIdx.x;
    if (e < N_EDGES) atomicAdd(&deg[dst[e]], 1);
}

// ---------- Kernel 3: single-block exclusive scan ----------
__global__ __launch_bounds__(1024) void scan_r12(const int* __restrict__ deg,
                                                 int* __restrict__ off,
                                                 int* __restrict__ woff)
{
    __shared__ int wsum[16];
    __shared__ int wexcl[16];
    __shared__ int carry_s;
    const int tid = threadIdx.x, lane = tid & 63, wid = tid >> 6;
    if (tid == 0) carry_s = 0;

    for (int base = 0; base < N_NODES; base += 8192) {
        __syncthreads();
        const int carry = carry_s;
        const int idx0 = base + tid * 8;
        int v[8];
        int local = 0;
        #pragma unroll
        for (int i = 0; i < 8; ++i) {
            int idx = idx0 + i;
            v[i] = (idx < N_NODES) ? deg[idx] : 0;
            local += v[i];
        }
        int sc = local;
        #pragma unroll
        for (int o = 1; o < 64; o <<= 1) {
            int t = __shfl_up(sc, o);
            if (lane >= o) sc += t;
        }
        if (lane == 63) wsum[wid] = sc;
        __syncthreads();
        if (tid == 0) {
            int run = 0;
            #pragma unroll
            for (int i = 0; i < 16; ++i) { wexcl[i] = run; run += wsum[i]; }
            carry_s = carry + run;
        }
        __syncthreads();
        int excl = carry + wexcl[wid] + (sc - local);
        #pragma unroll
        for (int i = 0; i < 8; ++i) {
            int idx = idx0 + i;
            if (idx < N_NODES) {
                off[idx] = excl;
                woff[idx] = excl;
                if (idx == N_NODES - 1) off[N_NODES] = excl + v[i];
            }
            excl += v[i];
        }
    }
}

// ---------- Kernel 4: scatter src ids into CSR order ----------
__global__ __launch_bounds__(256) void scatter_r12(const int* __restrict__ src,
                                                   const int* __restrict__ dst,
                                                   int* __restrict__ woff,
                                                   int* __restrict__ srcs)
{
    int e = blockIdx.x * 256 + threadIdx.x;
    if (e < N_EDGES) {
        int d = dst[e];
        int pos = atomicAdd(&woff[d], 1);
        srcs[pos] = src[e];
    }
}

// ---------- Kernel 5: fused Q/Skip + attention + LayerNorm ----------
// One wave per node. NEW: q[lane] and skip[lane] computed in-kernel from the
// feature row (wave-uniform address -> scalar loads) and g_WT columns
// (lane-contiguous 256B), eliminating the Qb/Sb buffers entirely.
__global__ __launch_bounds__(256) void attn_r12(
    const u16* __restrict__ F, const unsigned int* __restrict__ KV,
    const int* __restrict__ off, const int* __restrict__ srcs,
    const void* __restrict__ Wq, const void* __restrict__ bq,
    const void* __restrict__ Ws, const void* __restrict__ bs,
    const void* __restrict__ ln_g, const void* __restrict__ ln_b,
    void* __restrict__ out, const int* __restrict__ mode_p)
{
    const int mode = *mode_p;
    const int node = blockIdx.x * 4 + (threadIdx.x >> 6);
    const int lane = threadIdx.x & 63;

    float qv, sv;
    if (mode == 0) {
        const int node_u = __builtin_amdgcn_readfirstlane(node);
        const uint4* frow = reinterpret_cast<const uint4*>(F + (size_t)node_u * F_IN);
        const u16* wq = g_WT + 0 * HD * F_IN + lane * F_IN;
        const u16* ws = g_WT + 3 * HD * F_IN + lane * F_IN;
        float q = 0.f, s = 0.f;
        #pragma unroll
        for (int ks = 0; ks < 16; ++ks) {
            union { uint4 v; u16 u[8]; } f, a, b2;
            f.v  = frow[ks];
            a.v  = *reinterpret_cast<const uint4*>(wq + ks * 8);
            b2.v = *reinterpret_cast<const uint4*>(ws + ks * 8);
            #pragma unroll
            for (int j = 0; j < 8; ++j) {
                const float fv = bf2f(f.u[j]);
                q += fv * bf2f(a.u[j]);
                s += fv * bf2f(b2.u[j]);
            }
        }
        qv = (q + bf2f(((const u16*)bq)[lane])) * 0.25f;   // 1/sqrt(D=16)
        sv = s + bf2f(((const u16*)bs)[lane]);
    } else {
        const float* Ff  = (const float*)F;
        const float* Wqf = (const float*)Wq;
        const float* Wsf = (const float*)Ws;
        float q = 0.f, s = 0.f;
        for (int k = 0; k < F_IN; ++k) {
            const float fv = Ff[(size_t)node * F_IN + k];
            q += fv * Wqf[k * HD + lane];
            s += fv * Wsf[k * HD + lane];
        }
        qv = (q + ((const float*)bq)[lane]) * 0.25f;
        sv = s + ((const float*)bs)[lane];
    }

    const int e0 = off[node], e1 = off[node + 1];

    float z = 0.f, acc = 0.f;
    for (int base = e0; base < e1; base += 64) {
        const int n_e = min(64, e1 - base);
        int sidx = (base + lane < e1) ? srcs[base + lane] : 0;
        sidx = (sidx < 0) ? 0 : ((sidx >= N_NODES) ? N_NODES - 1 : sidx);
        int i = 0;
        for (; i + 4 <= n_e; i += 4) {
            const int s0 = __shfl(sidx, i);
            const int s1 = __shfl(sidx, i + 1);
            const int s2 = __shfl(sidx, i + 2);
            const int s3 = __shfl(sidx, i + 3);
            const unsigned int kv0 = KV[(size_t)s0 * HD + lane];
            const unsigned int kv1 = KV[(size_t)s1 * HD + lane];
            const unsigned int kv2 = KV[(size_t)s2 * HD + lane];
            const unsigned int kv3 = KV[(size_t)s3 * HD + lane];
            float p0 = qv * bf2f((u16)(kv0 & 0xffffu));
            float p1 = qv * bf2f((u16)(kv1 & 0xffffu));
            float p2 = qv * bf2f((u16)(kv2 & 0xffffu));
            float p3 = qv * bf2f((u16)(kv3 & 0xffffu));
            #pragma unroll
            for (int m = 1; m < 16; m <<= 1) {
                p0 += __shfl_xor(p0, m);
                p1 += __shfl_xor(p1, m);
                p2 += __shfl_xor(p2, m);
                p3 += __shfl_xor(p3, m);
            }
            const float x0 = __expf(p0);
            const float x1 = __expf(p1);
            const float x2 = __expf(p2);
            const float x3 = __expf(p3);
            z   += (x0 + x1) + (x2 + x3);
            acc += x0 * bf2f((u16)(kv0 >> 16)) + x1 * bf2f((u16)(kv1 >> 16))
                 + x2 * bf2f((u16)(kv2 >> 16)) + x3 * bf2f((u16)(kv3 >> 16));
        }
        for (; i < n_e; ++i) {
            const int s = __shfl(sidx, i);
            const unsigned int kv = KV[(size_t)s * HD + lane];
            float pz = qv * bf2f((u16)(kv & 0xffffu));
            #pragma unroll
            for (int m = 1; m < 16; m <<= 1) pz += __shfl_xor(pz, m);
            const float ex = __expf(pz);
            z   += ex;
            acc += ex * bf2f((u16)(kv >> 16));
        }
    }

    const float msg = (e1 > e0) ? (acc / z) : 0.f;
    float t = msg + sv;

    float mu = t;
    #pragma unroll
    for (int m = 1; m < 64; m <<= 1) mu += __shfl_xor(mu, m);
    mu *= (1.f / 64.f);
    const float d = t - mu;
    float var = d * d;
    #pragma unroll
    for (int m = 1; m < 64; m <<= 1) var += __shfl_xor(var, m);
    var *= (1.f / 64.f);
    const float r = d * rsqrtf(var + LN_EPS);

    const float g  = mode ? ((const float*)ln_g)[lane] : bf2f(((const u16*)ln_g)[lane]);
    const float bb = mode ? ((const float*)ln_b)[lane] : bf2f(((const u16*)ln_b)[lane]);
    const float res = r * g + bb;
    const size_t o = (size_t)node * HD + lane;
    if (mode) ((float*)out)[o] = res;
    else      ((u16*)out)[o]   = f2bf(res);
}

// ---------- launcher ----------
extern "C" void kernel_launch(void* const* d_in, const int* in_sizes, int n_in,
                              void* d_out, int out_size, void* d_ws, size_t ws_size,
                              hipStream_t stream)
{
    const void* feature = d_in[0];
    const int*  src     = (const int*)d_in[1];
    const int*  dst     = (const int*)d_in[2];
    const void* Wq = d_in[3];  const void* bq = d_in[4];
    const void* Wk = d_in[5];  const void* bk = d_in[6];
    const void* Wv = d_in[7];  const void* bv = d_in[8];
    const void* Ws = d_in[9];  const void* bs = d_in[10];
    const void* ln_g = d_in[11];
    const void* ln_b = d_in[12];

    // workspace: KV[N*64 u32] (25.6MB) then int arrays. ~33MB.
    unsigned int* KV = (unsigned int*)d_ws;
    int* deg  = (int*)(KV + (size_t)N_NODES * HD);
    int* off  = deg + N_NODES;
    int* woff = off + (N_NODES + 1);
    int* srcs = woff + N_NODES;
    int* mode = srcs + N_EDGES;

    const size_t need = (size_t)((char*)(mode + 1) - (char*)d_ws);
    if (ws_size < need) return;

    hipMemsetAsync(deg, 0, N_NODES * sizeof(int), stream);

    probe_r12<<<dim3(1), dim3(64), 0, stream>>>((const u16*)feature, mode);

    // CSR build first (independent of projection)
    hist_r12<<<dim3((N_EDGES + 255) / 256), dim3(256), 0, stream>>>(dst, deg);

    scan_r12<<<dim3(1), dim3(1024), 0, stream>>>(deg, off, woff);

    scatter_r12<<<dim3((N_EDGES + 255) / 256), dim3(256), 0, stream>>>(src, dst, woff, srcs);

    wtrans_r12<<<dim3(16), dim3(256), 0, stream>>>(Wq, Wk, Wv, Ws, mode);

    projkv_r12<<<dim3((N_NODES + 127) / 128), dim3(256), 0, stream>>>(
        feature, Wk, bk, Wv, bv, KV, mode);

    attn_r12<<<dim3(N_NODES / 4), dim3(256), 0, stream>>>(
        (const u16*)feature, KV, off, srcs, Wq, bq, Ws, bs, ln_g, ln_b, d_out, mode);
}

// Round 6
// 555.379 us; speedup vs baseline: 1.5547x; 1.5547x over previous
//
#include <hip/hip_runtime.h>

typedef unsigned short u16;
typedef __attribute__((ext_vector_type(8))) short short8;
typedef __attribute__((ext_vector_type(4))) float f32x4;

#define N_NODES 100000
#define N_EDGES 1600000
#define F_IN    128
#define HD      64
#define LN_EPS  1e-5f

#define HIST_BLOCKS  6250                 // N_EDGES / 256
#define PROJ_BLOCKS  1563                 // ceil(N_NODES / 64)
#define SCAT_BLOCKS  6250
#define SCAN_BLOCKS  98                   // ceil(N_NODES / 1024)

// Transposed weights: WT[m][col][k], 4 matrices x 64 cols x 128 k (u16 bf16).
__device__ u16 g_WT[4 * HD * F_IN];

// ---------- bf16 helpers ----------
__device__ __forceinline__ float bf2f(u16 u) {
    union { unsigned int i; float f; } x;
    x.i = ((unsigned int)u) << 16;
    return x.f;
}
__device__ __forceinline__ u16 f2bf(float f) {
    unsigned int u;
    __builtin_memcpy(&u, &f, 4);
    unsigned int r = u + 0x7FFFu + ((u >> 16) & 1u);   // RNE
    return (u16)(r >> 16);
}
__device__ __forceinline__ void ld4m(const void* p, int idx, int mode, float o[4]) {
    if (mode) {
        const float4 v = *reinterpret_cast<const float4*>((const float*)p + idx);
        o[0] = v.x; o[1] = v.y; o[2] = v.z; o[3] = v.w;
    } else {
        const ushort4 v = *reinterpret_cast<const ushort4*>((const u16*)p + idx);
        o[0] = bf2f(v.x); o[1] = bf2f(v.y); o[2] = bf2f(v.z); o[3] = bf2f(v.w);
    }
}

// ---------- Phase 1: {wtrans (16 blocks) | probe (1 block) | hist (6250)} ----
// All mutually independent. wtrans is unconditional (in fp32 mode g_WT holds
// garbage but is never read). probe writes mode, consumed in later dispatches.
__global__ __launch_bounds__(256) void fused1_r13(
    const int* __restrict__ dst, int* __restrict__ deg,
    const void* __restrict__ Wq, const void* __restrict__ Wk,
    const void* __restrict__ Wv, const void* __restrict__ Ws,
    const u16* __restrict__ feat, int* __restrict__ mode)
{
    const int bid = blockIdx.x;
    if (bid < 16) {
        // ---- wtrans: W[m] (128x64 bf16) -> g_WT[m] (64x128) ----
        const int m  = bid >> 2;
        const int kg = bid & 3;
        const u16* W = (const u16*)((m == 0) ? Wq : (m == 1) ? Wk
                                  : (m == 2) ? Wv : Ws);
        const int t  = threadIdx.x;
        const int k  = kg * 32 + (t >> 3);
        const int c0 = (t & 7) * 8;
        union { uint4 v; u16 s[8]; } row;
        row.v = *reinterpret_cast<const uint4*>(W + k * HD + c0);
        u16* outp = g_WT + m * HD * F_IN;
        #pragma unroll
        for (int j = 0; j < 8; ++j)
            outp[(c0 + j) * F_IN + k] = row.s[j];
    } else if (bid == 16) {
        // ---- probe ----
        const int lane = threadIdx.x;
        if (lane < 64) {
            float mx = 0.f;
            #pragma unroll
            for (int i = 0; i < 4; ++i)
                mx = fmaxf(mx, fabsf(bf2f(feat[lane * 4 + i])));
            #pragma unroll
            for (int o = 1; o < 64; o <<= 1) mx = fmaxf(mx, __shfl_xor(mx, o));
            if (lane == 0) *mode = (mx > 1000.f) ? 1 : 0;
        }
    } else {
        // ---- hist ----
        const int e = (bid - 17) * 256 + threadIdx.x;
        if (e < N_EDGES) atomicAdd(&deg[dst[e]], 1);
    }
}

// ---------- Phase 2a: block-local exclusive scan + block sums ----------
__global__ __launch_bounds__(1024) void scanA_r13(const int* __restrict__ deg,
                                                  int* __restrict__ off,
                                                  int* __restrict__ bsum)
{
    __shared__ int wsum[16];
    __shared__ int wexcl[16];
    const int tid = threadIdx.x, lane = tid & 63, wid = tid >> 6;
    const int idx = blockIdx.x * 1024 + tid;
    const int v = (idx < N_NODES) ? deg[idx] : 0;
    int sc = v;
    #pragma unroll
    for (int o = 1; o < 64; o <<= 1) {
        int t = __shfl_up(sc, o);
        if (lane >= o) sc += t;
    }
    if (lane == 63) wsum[wid] = sc;
    __syncthreads();
    if (tid == 0) {
        int run = 0;
        for (int i = 0; i < 16; ++i) { wexcl[i] = run; run += wsum[i]; }
        bsum[blockIdx.x] = run;
    }
    __syncthreads();
    if (idx < N_NODES) off[idx] = wexcl[wid] + (sc - v);
}

// ---------- Phase 2b: add block bases, finalize off/woff ----------
__global__ __launch_bounds__(1024) void scanC_r13(const int* __restrict__ deg,
                                                  int* __restrict__ off,
                                                  int* __restrict__ woff,
                                                  const int* __restrict__ bsum)
{
    __shared__ int base_s;
    const int tid = threadIdx.x;
    const int bid = blockIdx.x;
    if (tid == 0) {
        int run = 0;
        for (int i = 0; i < bid; ++i) run += bsum[i];
        base_s = run;
    }
    __syncthreads();
    const int base = base_s;
    const int idx = bid * 1024 + tid;
    if (idx < N_NODES) {
        const int e = off[idx] + base;
        off[idx]  = e;
        woff[idx] = e;
        if (idx == N_NODES - 1) off[N_NODES] = e + deg[idx];
    }
}

// ---------- Phase 3: {proj QKVS (1563 blocks) | scatter (6250)} interleaved --
// bid % 5 == 0 -> proj block (pid = bid/5); else scatter. Interleave keeps
// both populations resident so scatter's atomic/scattered-write latency fills
// proj's load-latency bubbles (and vice versa).
// proj body is r11's verified kernel verbatim (MFMA D = W^T F^T, swizzled LDS
// epilogue, coalesced uint4 stores, KV interleaved K-low/V-high).
__global__ __launch_bounds__(256) void fused2_r13(
    const void* __restrict__ feature,
    const void* __restrict__ Wq, const void* __restrict__ bq,
    const void* __restrict__ Wk, const void* __restrict__ bk,
    const void* __restrict__ Wv, const void* __restrict__ bv,
    const void* __restrict__ Ws, const void* __restrict__ bs,
    u16* __restrict__ Qb, unsigned int* __restrict__ KV, u16* __restrict__ Sb,
    const int* __restrict__ mode_p,
    const int* __restrict__ src, const int* __restrict__ dst,
    int* __restrict__ woff, int* __restrict__ srcs)
{
    __shared__ u16 lq[16 * 64];
    __shared__ u16 lk[16 * 64];
    __shared__ u16 lv[16 * 64];
    __shared__ u16 ls[16 * 64];

    const int bid = blockIdx.x;

    if (bid % 5 != 0) {
        // ---------------- scatter ----------------
        const int sid = bid - bid / 5 - 1;
        const int e = sid * 256 + threadIdx.x;
        if (e < N_EDGES) {
            const int d = dst[e];
            const int pos = atomicAdd(&woff[d], 1);
            srcs[pos] = src[e];
        }
        return;
    }

    // ---------------- proj ----------------
    const int pid  = bid / 5;
    const int mode = *mode_p;
    const int tid  = threadIdx.x;
    const int w    = tid >> 6;
    const int lane = tid & 63;

    const void* W;
    const void* b;
    float scale = 1.0f;
    if      (w == 0) { W = Wq; b = bq; scale = 0.25f; }  // 1/sqrt(D=16)
    else if (w == 1) { W = Wk; b = bk; }
    else if (w == 2) { W = Wv; b = bv; }
    else             { W = Ws; b = bs; }

    if (mode == 0) {
        const u16* F = (const u16*)feature;
        const int h = lane >> 4;    // 0..3
        const int c = lane & 15;    // 0..15

        const u16* WT = g_WT + w * HD * F_IN;
        short8 wfrag[4][4];
        #pragma unroll
        for (int ct = 0; ct < 4; ++ct) {
            const int col = ct * 16 + c;
            #pragma unroll
            for (int ks = 0; ks < 4; ++ks)
                wfrag[ct][ks] = *reinterpret_cast<const short8*>(
                    WT + col * F_IN + ks * 32 + h * 8);
        }

        float bias_f[4][4];
        #pragma unroll
        for (int ct = 0; ct < 4; ++ct) {
            const ushort4 bu =
                *reinterpret_cast<const ushort4*>((const u16*)b + ct * 16 + h * 4);
            bias_f[ct][0] = bf2f(bu.x); bias_f[ct][1] = bf2f(bu.y);
            bias_f[ct][2] = bf2f(bu.z); bias_f[ct][3] = bf2f(bu.w);
        }

        u16* Lmine = (w == 0) ? lq : (w == 1) ? lk : (w == 2) ? lv : ls;

        short8 fr[2][4];
        {
            const size_t arow = (size_t)(pid * 64 + c) * F_IN;
            #pragma unroll
            for (int ks = 0; ks < 4; ++ks)
                fr[0][ks] = *reinterpret_cast<const short8*>(F + arow + ks * 32 + h * 8);
        }

        #pragma unroll
        for (int t = 0; t < 4; ++t) {
            const int nbase = pid * 64 + t * 16;
            if (nbase >= N_NODES) break;          // uniform across block
            const int cur = t & 1, nxt = cur ^ 1;

            const int nb2 = nbase + 16;
            if (t < 3 && nb2 < N_NODES) {
                const size_t arow = (size_t)(nb2 + c) * F_IN;
                #pragma unroll
                for (int ks = 0; ks < 4; ++ks)
                    fr[nxt][ks] =
                        *reinterpret_cast<const short8*>(F + arow + ks * 32 + h * 8);
            }

            f32x4 acc[4];
            #pragma unroll
            for (int ct = 0; ct < 4; ++ct) acc[ct] = (f32x4){0.f, 0.f, 0.f, 0.f};
            #pragma unroll
            for (int ks = 0; ks < 4; ++ks)
                #pragma unroll
                for (int ct = 0; ct < 4; ++ct)
                    acc[ct] = __builtin_amdgcn_mfma_f32_16x16x32_bf16(
                        wfrag[ct][ks], fr[cur][ks], acc[ct], 0, 0, 0);

            #pragma unroll
            for (int ct = 0; ct < 4; ++ct) {
                ushort4 pk;
                pk.x = f2bf((acc[ct][0] + bias_f[ct][0]) * scale);
                pk.y = f2bf((acc[ct][1] + bias_f[ct][1]) * scale);
                pk.z = f2bf((acc[ct][2] + bias_f[ct][2]) * scale);
                pk.w = f2bf((acc[ct][3] + bias_f[ct][3]) * scale);
                const int bo = (ct * 32 + h * 8) ^ ((c & 7) << 4);
                *reinterpret_cast<ushort4*>(
                    reinterpret_cast<char*>(Lmine) + c * 128 + bo) = pk;
            }
            __syncthreads();

            {
                const int half = tid >> 7;
                const int tt   = tid & 127;
                const int row  = tt >> 3, seg = tt & 7;
                const int ro   = (seg * 16) ^ ((row & 7) << 4);
                const uint4 qs = *reinterpret_cast<const uint4*>(
                    reinterpret_cast<const char*>(half ? ls : lq) + row * 128 + ro);
                *reinterpret_cast<uint4*>(
                    (half ? Sb : Qb) + (size_t)(nbase + row) * HD + seg * 8) = qs;

                const int krow = tid >> 4, c4 = tid & 15;
                const int ko   = (c4 * 8) ^ ((krow & 7) << 4);
                const ushort4 kk = *reinterpret_cast<const ushort4*>(
                    reinterpret_cast<const char*>(lk) + krow * 128 + ko);
                const ushort4 vv = *reinterpret_cast<const ushort4*>(
                    reinterpret_cast<const char*>(lv) + krow * 128 + ko);
                uint4 o;
                o.x = (unsigned)kk.x | ((unsigned)vv.x << 16);
                o.y = (unsigned)kk.y | ((unsigned)vv.y << 16);
                o.z = (unsigned)kk.z | ((unsigned)vv.z << 16);
                o.w = (unsigned)kk.w | ((unsigned)vv.w << 16);
                *reinterpret_cast<uint4*>(
                    KV + (size_t)(nbase + krow) * HD + c4 * 4) = o;
            }
            __syncthreads();
        }
    } else {
        // ---------- fp32 fallback (inert in practice) ----------
        const int colg  = lane & 15;
        const int nodeg = lane >> 4;
        const int c0    = colg * 4;
        const int kvsub = (w == 1) ? 0 : 1;
        u16* KVu = (u16*)KV;

        for (int st = 0; st < 4; ++st) {
            if (pid * 64 + st * 16 >= N_NODES) break;
            const int node_base = pid * 64 + st * 16 + nodeg * 4;

            float acc[4][4];
            #pragma unroll
            for (int n = 0; n < 4; ++n)
                #pragma unroll
                for (int cc = 0; cc < 4; ++cc) acc[n][cc] = 0.f;

            for (int k = 0; k < F_IN; k += 4) {
                float wv4[4][4];
                #pragma unroll
                for (int kk = 0; kk < 4; ++kk)
                    ld4m(W, (k + kk) * HD + c0, 1, wv4[kk]);
                #pragma unroll
                for (int n = 0; n < 4; ++n) {
                    float f[4];
                    ld4m(feature, (node_base + n) * F_IN + k, 1, f);
                    #pragma unroll
                    for (int cc = 0; cc < 4; ++cc)
                        acc[n][cc] += f[0] * wv4[0][cc] + f[1] * wv4[1][cc]
                                    + f[2] * wv4[2][cc] + f[3] * wv4[3][cc];
                }
            }

            float bias[4];
            ld4m(b, c0, 1, bias);

            #pragma unroll
            for (int n = 0; n < 4; ++n) {
                const int node = node_base + n;
                u16 r[4];
                #pragma unroll
                for (int cc = 0; cc < 4; ++cc)
                    r[cc] = f2bf((acc[n][cc] + bias[cc]) * scale);

                if (w == 0 || w == 3) {
                    u16* O = (w == 0) ? Qb : Sb;
                    ushort4 u4; u4.x = r[0]; u4.y = r[1]; u4.z = r[2]; u4.w = r[3];
                    *reinterpret_cast<ushort4*>(O + (size_t)node * HD + c0) = u4;
                } else {
                    #pragma unroll
                    for (int cc = 0; cc < 4; ++cc)
                        KVu[(size_t)node * 2 * HD + 2 * (c0 + cc) + kvsub] = r[cc];
                }
            }
        }
    }
}

// ---------- Phase 4: attention + skip + LayerNorm (r11 verbatim) ----------
__global__ __launch_bounds__(256) void attn_r13(
    const u16* __restrict__ Qb, const unsigned int* __restrict__ KV,
    const u16* __restrict__ Sb,
    const int* __restrict__ off, const int* __restrict__ srcs,
    const void* __restrict__ ln_g, const void* __restrict__ ln_b,
    void* __restrict__ out, const int* __restrict__ mode_p)
{
    const int mode = *mode_p;
    const int node = blockIdx.x * 4 + (threadIdx.x >> 6);
    const int lane = threadIdx.x & 63;

    const float qv = bf2f(Qb[(size_t)node * HD + lane]);
    const int e0 = off[node], e1 = off[node + 1];

    float z = 0.f, acc = 0.f;
    for (int base = e0; base < e1; base += 64) {
        const int n_e = min(64, e1 - base);
        int sidx = (base + lane < e1) ? srcs[base + lane] : 0;
        sidx = (sidx < 0) ? 0 : ((sidx >= N_NODES) ? N_NODES - 1 : sidx);
        int i = 0;
        for (; i + 4 <= n_e; i += 4) {
            const int s0 = __shfl(sidx, i);
            const int s1 = __shfl(sidx, i + 1);
            const int s2 = __shfl(sidx, i + 2);
            const int s3 = __shfl(sidx, i + 3);
            const unsigned int kv0 = KV[(size_t)s0 * HD + lane];
            const unsigned int kv1 = KV[(size_t)s1 * HD + lane];
            const unsigned int kv2 = KV[(size_t)s2 * HD + lane];
            const unsigned int kv3 = KV[(size_t)s3 * HD + lane];
            float p0 = qv * bf2f((u16)(kv0 & 0xffffu));
            float p1 = qv * bf2f((u16)(kv1 & 0xffffu));
            float p2 = qv * bf2f((u16)(kv2 & 0xffffu));
            float p3 = qv * bf2f((u16)(kv3 & 0xffffu));
            #pragma unroll
            for (int m = 1; m < 16; m <<= 1) {
                p0 += __shfl_xor(p0, m);
                p1 += __shfl_xor(p1, m);
                p2 += __shfl_xor(p2, m);
                p3 += __shfl_xor(p3, m);
            }
            const float x0 = __expf(p0);
            const float x1 = __expf(p1);
            const float x2 = __expf(p2);
            const float x3 = __expf(p3);
            z   += (x0 + x1) + (x2 + x3);
            acc += x0 * bf2f((u16)(kv0 >> 16)) + x1 * bf2f((u16)(kv1 >> 16))
                 + x2 * bf2f((u16)(kv2 >> 16)) + x3 * bf2f((u16)(kv3 >> 16));
        }
        for (; i < n_e; ++i) {
            const int s = __shfl(sidx, i);
            const unsigned int kv = KV[(size_t)s * HD + lane];
            float p = qv * bf2f((u16)(kv & 0xffffu));
            #pragma unroll
            for (int m = 1; m < 16; m <<= 1) p += __shfl_xor(p, m);
            const float ex = __expf(p);
            z   += ex;
            acc += ex * bf2f((u16)(kv >> 16));
        }
    }

    const float msg = (e1 > e0) ? (acc / z) : 0.f;
    float t = msg + bf2f(Sb[(size_t)node * HD + lane]);

    float mu = t;
    #pragma unroll
    for (int m = 1; m < 64; m <<= 1) mu += __shfl_xor(mu, m);
    mu *= (1.f / 64.f);
    const float d = t - mu;
    float var = d * d;
    #pragma unroll
    for (int m = 1; m < 64; m <<= 1) var += __shfl_xor(var, m);
    var *= (1.f / 64.f);
    const float r = d * rsqrtf(var + LN_EPS);

    const float g  = mode ? ((const float*)ln_g)[lane] : bf2f(((const u16*)ln_g)[lane]);
    const float bb = mode ? ((const float*)ln_b)[lane] : bf2f(((const u16*)ln_b)[lane]);
    const float res = r * g + bb;
    const size_t o = (size_t)node * HD + lane;
    if (mode) ((float*)out)[o] = res;
    else      ((u16*)out)[o]   = f2bf(res);
}

// ---------- launcher ----------
extern "C" void kernel_launch(void* const* d_in, const int* in_sizes, int n_in,
                              void* d_out, int out_size, void* d_ws, size_t ws_size,
                              hipStream_t stream)
{
    const void* feature = d_in[0];
    const int*  src     = (const int*)d_in[1];
    const int*  dst     = (const int*)d_in[2];
    const void* Wq = d_in[3];  const void* bq = d_in[4];
    const void* Wk = d_in[5];  const void* bk = d_in[6];
    const void* Wv = d_in[7];  const void* bv = d_in[8];
    const void* Ws = d_in[9];  const void* bs = d_in[10];
    const void* ln_g = d_in[11];
    const void* ln_b = d_in[12];

    // workspace: Qb | KV | Sb bf16/u32, then int arrays. ~59 MB.
    u16* Qb = (u16*)d_ws;
    unsigned int* KV = (unsigned int*)(Qb + (size_t)N_NODES * HD);
    u16* Sb = (u16*)(KV + (size_t)N_NODES * HD);
    int* deg  = (int*)(Sb + (size_t)N_NODES * HD);
    int* off  = deg + N_NODES;
    int* woff = off + (N_NODES + 1);
    int* srcs = woff + N_NODES;
    int* mode = srcs + N_EDGES;
    int* bsum = mode + 1;

    const size_t need = (size_t)((char*)(bsum + SCAN_BLOCKS) - (char*)d_ws);
    if (ws_size < need) return;

    hipMemsetAsync(deg, 0, N_NODES * sizeof(int), stream);

    // P1: wtrans | probe | hist (independent)
    fused1_r13<<<dim3(17 + HIST_BLOCKS), dim3(256), 0, stream>>>(
        dst, deg, Wq, Wk, Wv, Ws, (const u16*)feature, mode);

    // P2: parallel scan
    scanA_r13<<<dim3(SCAN_BLOCKS), dim3(1024), 0, stream>>>(deg, off, bsum);
    scanC_r13<<<dim3(SCAN_BLOCKS), dim3(1024), 0, stream>>>(deg, off, woff, bsum);

    // P3: proj | scatter (independent), 5-way interleaved
    fused2_r13<<<dim3(PROJ_BLOCKS + SCAT_BLOCKS), dim3(256), 0, stream>>>(
        feature, Wq, bq, Wk, bk, Wv, bv, Ws, bs,
        Qb, KV, Sb, mode, src, dst, woff, srcs);

    // P4: attention
    attn_r13<<<dim3(N_NODES / 4), dim3(256), 0, stream>>>(
        Qb, KV, Sb, off, srcs, ln_g, ln_b, d_out, mode);
}